// Round 7
// baseline (113.673 us; speedup 1.0000x reference)
//
#include <hip/hip_runtime.h>
#include <hip/hip_bf16.h>

#define N 4096
#define D 128
#define TILE 128
#define NFF 4096.0f

typedef __attribute__((ext_vector_type(8))) short short8;
typedef __attribute__((ext_vector_type(4))) float f32x4;

#define LOG2E 1.44269504088896340736f
#define LN2   0.69314718055994530942f

#if __has_builtin(__builtin_amdgcn_rcpf)
__device__ __forceinline__ float fast_rcp(float x) { return __builtin_amdgcn_rcpf(x); }
#else
__device__ __forceinline__ float fast_rcp(float x) { return 1.f / x; }
#endif
#if __has_builtin(__builtin_amdgcn_logf)
__device__ __forceinline__ float fast_log2(float x) { return __builtin_amdgcn_logf(x); }
#else
__device__ __forceinline__ float fast_log2(float x) { return __log2f(x); }
#endif
#if __has_builtin(__builtin_amdgcn_exp2f)
__device__ __forceinline__ float fast_exp2(float x) { return __builtin_amdgcn_exp2f(x); }
#else
__device__ __forceinline__ float fast_exp2(float x) { return exp2f(x); }
#endif

__device__ __forceinline__ float sigx(float x) {   // sigmoid(x)
    return fast_rcp(1.f + fast_exp2(-x * LOG2E));
}

__device__ __forceinline__ short bf16_of(float v) {
    __hip_bfloat16 h = __float2bfloat16(v);
    return *reinterpret_cast<short*>(&h);
}

__device__ __forceinline__ short8 pack8(float4 a, float4 b) {
    short8 r;
    r[0] = bf16_of(a.x); r[1] = bf16_of(a.y); r[2] = bf16_of(a.z); r[3] = bf16_of(a.w);
    r[4] = bf16_of(b.x); r[5] = bf16_of(b.y); r[6] = bf16_of(b.z); r[7] = bf16_of(b.w);
    return r;
}

__device__ __forceinline__ float sq8(float4 a, float4 b, float acc) {
    acc = fmaf(a.x, a.x, acc); acc = fmaf(a.y, a.y, acc);
    acc = fmaf(a.z, a.z, acc); acc = fmaf(a.w, a.w, acc);
    acc = fmaf(b.x, b.x, acc); acc = fmaf(b.y, b.y, acc);
    acc = fmaf(b.z, b.z, acc); acc = fmaf(b.w, b.w, acc);
    return acc;
}

// ---------------- k_main: fp32 load + in-reg bf16 cvt + in-reg norms + MFMA + moment epilogue ----------------
// Barrier-free, LDS-free, atomic-free. Block (bm,bn): i-band row0=bm*128 (Y), j-band col0=bn*128 (X).
// acc[a][b][r]: j = col0 + wj + a*16 + quad*4 + r,  i = row0 + wi + b*16 + l16
// Per-wave partial slot: part[((bm*32+bn)*4 + wave)*320 + v*64 + (b*16+l16)], v in {E, C1..C4}
__global__ __launch_bounds__(256) void k_main(
    const float* __restrict__ X, const float* __restrict__ Y,
    float* __restrict__ pos, float* __restrict__ part,
    float* __restrict__ sc, int* __restrict__ syncv)
{
    const int tid = threadIdx.x;
    const int bm = blockIdx.y, bn = blockIdx.x;
    if (bm == 0 && bn == 0) {
        if (tid < 16) sc[tid] = 0.f;
        else if (tid < 20) syncv[tid - 16] = 0;
    }
    const int row0 = bm * TILE, col0 = bn * TILE;
    const int lane = tid & 63, wave = tid >> 6;
    const int wj = (wave >> 1) * 64, wi = (wave & 1) * 64;
    const int l16 = lane & 15, quad = lane >> 4;

    f32x4 acc[4][4];
#pragma unroll
    for (int a = 0; a < 4; a++)
#pragma unroll
        for (int b = 0; b < 4; b++) acc[a][b] = f32x4{0.f, 0.f, 0.f, 0.f};

    float nA[4] = {0.f, 0.f, 0.f, 0.f}, nB[4] = {0.f, 0.f, 0.f, 0.f};

    const float* Xb0 = X + (size_t)(col0 + wj + l16) * D + quad * 8;   // j side (A)
    const float* Yb0 = Y + (size_t)(row0 + wi + l16) * D + quad * 8;   // i side (B)

#pragma unroll
    for (int kk = 0; kk < 4; ++kk) {
        short8 af[4], bf[4];
#pragma unroll
        for (int t = 0; t < 4; t++) {
            const float* xr = Xb0 + (size_t)(t * 16) * D + kk * 32;
            float4 u0 = *(const float4*)xr, u1 = *(const float4*)(xr + 4);
            nA[t] = sq8(u0, u1, nA[t]);
            af[t] = pack8(u0, u1);
            const float* yr = Yb0 + (size_t)(t * 16) * D + kk * 32;
            float4 v0 = *(const float4*)yr, v1 = *(const float4*)(yr + 4);
            nB[t] = sq8(v0, v1, nB[t]);
            bf[t] = pack8(v0, v1);
        }
#pragma unroll
        for (int a = 0; a < 4; a++)
#pragma unroll
            for (int b = 0; b < 4; b++)
                acc[a][b] = __builtin_amdgcn_mfma_f32_16x16x32_bf16(af[a], bf[b], acc[a][b], 0, 0, 0);
    }

    // reduce per-row norms across the 4 quad-lanes (each holds 32 of the row's 128 elems)
#pragma unroll
    for (int t = 0; t < 4; t++) {
        nA[t] += __shfl_xor(nA[t], 16); nA[t] += __shfl_xor(nA[t], 32);
        nB[t] += __shfl_xor(nB[t], 16); nB[t] += __shfl_xor(nB[t], 32);
    }

    float sE[4] = {0.f, 0.f, 0.f, 0.f}, s1[4] = {0.f, 0.f, 0.f, 0.f};
    float s2[4] = {0.f, 0.f, 0.f, 0.f}, s3[4] = {0.f, 0.f, 0.f, 0.f}, s4[4] = {0.f, 0.f, 0.f, 0.f};
    const bool diagw = (bm == bn) && (wi == wj);

#pragma unroll
    for (int a = 0; a < 4; a++) {
        // xnv[r] = norm of j-row (a, quad*4+r), fetched from the lane in this 16-group holding it
        f32x4 x1;
#pragma unroll
        for (int r = 0; r < 4; r++) x1[r] = __shfl(nA[a], quad * 4 + r, 16) + 1.f;
#pragma unroll
        for (int b = 0; b < 4; b++) {
#pragma unroll
            for (int r = 0; r < 4; r++) {
                float t = fmaxf(fmaf(-2.f, acc[a][b][r], nB[b] + x1[r]), 1.f);
                float e = fast_rcp(t);                        // e^L exactly
                float c = fast_log2(t * 0.00390625f);         // log2(t) - 8, centered
                float c2 = c * c;
                sE[b] += e;
                s1[b] += c;
                s2[b] += c2;
                s3[b] = fmaf(c, c2, s3[b]);
                s4[b] = fmaf(c2, c2, s4[b]);
                if (diagw && (a * 16 + quad * 4 + r) == (b * 16 + l16))
                    pos[row0 + wi + b * 16 + l16] = -LN2 * (c + 8.f);
            }
        }
    }

    // reduce over the 4 j-subtiles' lanes (xor 16/32), then plain coalesced partial store
#pragma unroll
    for (int b = 0; b < 4; b++) {
        sE[b] += __shfl_xor(sE[b], 16); sE[b] += __shfl_xor(sE[b], 32);
        s1[b] += __shfl_xor(s1[b], 16); s1[b] += __shfl_xor(s1[b], 32);
        s2[b] += __shfl_xor(s2[b], 16); s2[b] += __shfl_xor(s2[b], 32);
        s3[b] += __shfl_xor(s3[b], 16); s3[b] += __shfl_xor(s3[b], 32);
        s4[b] += __shfl_xor(s4[b], 16); s4[b] += __shfl_xor(s4[b], 32);
    }
    if (lane < 16) {
        float* pw = part + ((size_t)((bm * 32 + bn) * 4 + wave)) * 320;
#pragma unroll
        for (int b = 0; b < 4; b++) {
            const int o = b * 16 + l16;
            pw[0 * 64 + o] = sE[b];
            pw[1 * 64 + o] = s1[b];
            pw[2 * 64 + o] = s2[b];
            pw[3 * 64 + o] = s3[b];
            pw[4 * 64 + o] = s4[b];
        }
    }
}

// ---------------- block reduction helper ----------------
__device__ __forceinline__ float block_sum(float v, float* sm)
{
#pragma unroll
    for (int m = 1; m < 64; m <<= 1) v += __shfl_xor(v, m);
    if ((threadIdx.x & 63) == 0) sm[threadIdx.x >> 6] = v;
    __syncthreads();
    float r = 0.f;
    if (threadIdx.x == 0) r = sm[0] + sm[1] + sm[2] + sm[3];
    __syncthreads();
    return r;  // valid on thread 0
}

// ---------------- k_post: partial-reduce + LB (exact) + moment-based W/P/Q + outputs ----------------
__global__ __launch_bounds__(256) void k_post(
    const float* __restrict__ pos, const float* __restrict__ part,
    float* __restrict__ sc, int* __restrict__ syncv, float* __restrict__ out)
{
    __shared__ float sm[4];
    __shared__ float sLB;
    const int tid = threadIdx.x;
    const int i = blockIdx.x * 256 + tid;
    const int nb = gridDim.x;

    // ---- reduce this row's 64 per-wave partials (32 bn x 2 wj) ----
    const int bmq = i >> 7, il = i & 127, il64 = il & 63, w0 = il >> 6;
    float A5[5] = {0.f, 0.f, 0.f, 0.f, 0.f};
    for (int bn2 = 0; bn2 < 32; ++bn2) {
#pragma unroll
        for (int wjj = 0; wjj < 2; ++wjj) {
            const float* q = part + ((size_t)((bmq * 32 + bn2) * 4 + (wjj << 1) + w0)) * 320 + il64;
#pragma unroll
            for (int v = 0; v < 5; ++v) A5[v] += q[v * 64];
        }
    }
    const float E = A5[0], C1 = A5[1];

    const float p  = pos[i];
    const float pe = fast_exp2(p * LOG2E);

    // ---- phase A: exact global reductions -> LB ----
    float bs;
    bs = block_sum(pe, sm);                            if (tid == 0) atomicAdd(&sc[10], bs);
    bs = block_sum(E - pe, sm);                        if (tid == 0) atomicAdd(&sc[11], bs);
    bs = block_sum(-LN2 * (8.f * NFF + C1) - p, sm);   if (tid == 0) atomicAdd(&sc[12], bs);
    bs = block_sum(p, sm);                             if (tid == 0) atomicAdd(&sc[13], bs);
    __threadfence();
    if (tid == 0) {
        int c = __hip_atomic_fetch_add(&syncv[0], 1, __ATOMIC_ACQ_REL, __HIP_MEMORY_SCOPE_AGENT);
        if (c == nb - 1) {
            float S_pos = __hip_atomic_load(&sc[10], __ATOMIC_RELAXED, __HIP_MEMORY_SCOPE_AGENT);
            float S_neg = __hip_atomic_load(&sc[11], __ATOMIC_RELAXED, __HIP_MEMORY_SCOPE_AGENT);
            float TLs   = __hip_atomic_load(&sc[12], __ATOMIC_RELAXED, __HIP_MEMORY_SCOPE_AGENT);
            float Sp    = __hip_atomic_load(&sc[13], __ATOMIC_RELAXED, __HIP_MEMORY_SCOPE_AGENT);
            const float logM = __logf(NFF * (NFF - 1.f));
            float lb2 = __logf(S_neg) - logM;
            float lb1 = __logf(0.5f * ((NFF - 1.f) * S_pos + S_neg)) - logM;
            float LB = lb1 + lb2;
            __hip_atomic_store(&sc[3], LB,  __ATOMIC_RELAXED, __HIP_MEMORY_SCOPE_AGENT);
            __hip_atomic_store(&sc[4], Sp,  __ATOMIC_RELAXED, __HIP_MEMORY_SCOPE_AGENT);
            __hip_atomic_store(&sc[5], TLs, __ATOMIC_RELAXED, __HIP_MEMORY_SCOPE_AGENT);
            __hip_atomic_store(&syncv[1], 1, __ATOMIC_RELEASE, __HIP_MEMORY_SCOPE_AGENT);
        }
        while (__hip_atomic_load(&syncv[1], __ATOMIC_ACQUIRE, __HIP_MEMORY_SCOPE_AGENT) == 0)
            __builtin_amdgcn_s_sleep(8);
        sLB = __hip_atomic_load(&sc[3], __ATOMIC_RELAXED, __HIP_MEMORY_SCOPE_AGENT);
    }
    __syncthreads();
    const float LB = sLB;

    // ---- exact per-row: TP term and diagonal corrections ----
    float Roff = E - pe;
    float pf = p - LB + __logf(0.5f * ((NFF - 1.f) * pe + Roff)) - __logf(NFF - 1.f);
    float tp  = sigx(pf);
    float sgd = sigx(2.f * p - LB);

    // ---- moment-based row sums (4th-order Taylor about row mean of l) ----
    const float inN = 1.f / NFF;
    float m1 = C1 * inN, e2 = A5[2] * inN, e3 = A5[3] * inN, e4 = A5[4] * inN;
    float k2 = e2 - m1 * m1;
    float k3 = e3 - 3.f * m1 * e2 + 2.f * m1 * m1 * m1;
    float k4 = e4 - 4.f * m1 * e3 + 6.f * m1 * m1 * e2 - 3.f * m1 * m1 * m1 * m1;
    float mu2 = LN2 * LN2 * k2;
    float mu3 = -LN2 * LN2 * LN2 * k3;
    float mu4 = LN2 * LN2 * LN2 * LN2 * k4;
    float mlam = 8.f + m1;                 // mean log2(t)
    float ml = -LN2 * mlam;                // mean l
    float eml = fast_exp2(-mlam);          // e^{ml}
    float den = pe + eml;
    float s = eml * fast_rcp(den);         // sigma(ml - p) = way'
    float w = LN2 * (fast_log2(den) - 1.f);  // way(ml)
    float s1d = s * (1.f - s);
    float a2 = s1d, a3 = s1d * (1.f - 2.f * s), a4 = s1d * (1.f - 6.f * s1d);

    float g = sigx(p + w - LB);
    float g1 = g * (1.f - g), g2 = g1 * (1.f - 2.f * g), g3 = g1 * (1.f - 6.f * g1);
    float g4 = g1 * (1.f - 2.f * g) * (1.f - 12.f * g1);
    float ss = s * s;
    float FP2 = g2 * ss + g1 * a2;
    float FP3 = g3 * ss * s + 3.f * g2 * s * a2 + g1 * a3;
    float FP4 = g4 * ss * ss + 6.f * g3 * ss * a2 + g2 * (3.f * a2 * a2 + 4.f * s * a3) + g1 * a4;

    float h = sigx(w + ml - LB);
    float h1 = h * (1.f - h), h2 = h1 * (1.f - 2.f * h), h3 = h1 * (1.f - 6.f * h1);
    float h4 = h1 * (1.f - 2.f * h) * (1.f - 12.f * h1);
    float b1 = 1.f + s, bb = b1 * b1;
    float FQ2 = h2 * bb + h1 * a2;
    float FQ3 = h3 * bb * b1 + 3.f * h2 * b1 * a2 + h1 * a3;
    float FQ4 = h4 * bb * bb + 6.f * h3 * bb * a2 + h2 * (3.f * a2 * a2 + 4.f * b1 * a3) + h1 * a4;

    float Wi = NFF * (w + 0.5f * a2 * mu2 + (1.f / 6.f) * a3 * mu3 + (1.f / 24.f) * a4 * mu4);
    float Pi = NFF * (g + 0.5f * FP2 * mu2 + (1.f / 6.f) * FP3 * mu3 + (1.f / 24.f) * FP4 * mu4);
    float Qi = NFF * (h + 0.5f * FQ2 * mu2 + (1.f / 6.f) * FQ3 * mu3 + (1.f / 24.f) * FQ4 * mu4);

    bs = block_sum(Wi, sm);  if (tid == 0) atomicAdd(&sc[0], bs);
    bs = block_sum(Pi, sm);  if (tid == 0) atomicAdd(&sc[1], bs);
    bs = block_sum(Qi, sm);  if (tid == 0) atomicAdd(&sc[2], bs);
    bs = block_sum(tp, sm);  if (tid == 0) atomicAdd(&sc[6], bs);
    bs = block_sum(sgd, sm); if (tid == 0) atomicAdd(&sc[7], bs);
    __threadfence();
    if (tid == 0) {
        int c = __hip_atomic_fetch_add(&syncv[2], 1, __ATOMIC_ACQ_REL, __HIP_MEMORY_SCOPE_AGENT);
        if (c == nb - 1) {
            float W   = __hip_atomic_load(&sc[0], __ATOMIC_RELAXED, __HIP_MEMORY_SCOPE_AGENT);
            float P   = __hip_atomic_load(&sc[1], __ATOMIC_RELAXED, __HIP_MEMORY_SCOPE_AGENT);
            float Q   = __hip_atomic_load(&sc[2], __ATOMIC_RELAXED, __HIP_MEMORY_SCOPE_AGENT);
            float tps = __hip_atomic_load(&sc[6], __ATOMIC_RELAXED, __HIP_MEMORY_SCOPE_AGENT);
            float sg  = __hip_atomic_load(&sc[7], __ATOMIC_RELAXED, __HIP_MEMORY_SCOPE_AGENT);
            float Sp  = __hip_atomic_load(&sc[4], __ATOMIC_RELAXED, __HIP_MEMORY_SCOPE_AGENT);
            float TLs = __hip_atomic_load(&sc[5], __ATOMIC_RELAXED, __HIP_MEMORY_SCOPE_AGENT);
            const float M = NFF * (NFF - 1.f);
            float Wo  = W - Sp;          // off-diagonal sum of way
            float SGP = P - sg;
            float SGN = Q - sg;
            float TP = tps * (1.f / NFF);
            float o0 = Sp / NFF + Wo / M - LB;
            float o1 = Wo / M + TLs / M - LB;
            float o2 = SGP / M, o3 = SGN / M;
            out[0] = o0;
            out[1] = o1;
            out[2] = o2;
            out[3] = o3;
            out[4] = (TP + 1.f - o3) * 0.5f;
            out[5] = TP;
            out[6] = TP / (TP + o3);
            out[7] = LB;
            out[8] = -o0 + 2.0f;
        }
    }
}

extern "C" void kernel_launch(void* const* d_in, const int* in_sizes, int n_in,
                              void* d_out, int out_size, void* d_ws, size_t ws_size,
                              hipStream_t stream)
{
    const float* X = (const float*)d_in[0];  // z_x (j / columns of logits)
    const float* Y = (const float*)d_in[1];  // z_y (i / rows of logits)
    float* out = (float*)d_out;

    char* ws = (char*)d_ws;
    float* pos   = (float*)ws;                 // N floats
    float* sc    = pos + N;                    // 16 scalars
    int*   syncv = (int*)(sc + 16);            // 4 ints
    float* part  = (float*)(ws + (1 << 20));   // 1024 blocks * 4 waves * 5 * 64 floats = 5.24 MB

    k_main<<<dim3(N / TILE, N / TILE), 256, 0, stream>>>(X, Y, pos, part, sc, syncv);
    k_post<<<16, 256, 0, stream>>>(pos, part, sc, syncv, out);
}

// Round 8
// 104.944 us; speedup vs baseline: 1.0832x; 1.0832x over previous
//
#include <hip/hip_runtime.h>
#include <hip/hip_bf16.h>

#define N 4096
#define D 128
#define TILE 128
#define NFF 4096.0f

typedef __attribute__((ext_vector_type(8))) short short8;
typedef __attribute__((ext_vector_type(4))) float f32x4;

#define LOG2E 1.44269504088896340736f
#define LN2   0.69314718055994530942f

#if __has_builtin(__builtin_amdgcn_rcpf)
__device__ __forceinline__ float fast_rcp(float x) { return __builtin_amdgcn_rcpf(x); }
#else
__device__ __forceinline__ float fast_rcp(float x) { return 1.f / x; }
#endif
#if __has_builtin(__builtin_amdgcn_logf)
__device__ __forceinline__ float fast_log2(float x) { return __builtin_amdgcn_logf(x); }
#else
__device__ __forceinline__ float fast_log2(float x) { return __log2f(x); }
#endif
#if __has_builtin(__builtin_amdgcn_exp2f)
__device__ __forceinline__ float fast_exp2(float x) { return __builtin_amdgcn_exp2f(x); }
#else
__device__ __forceinline__ float fast_exp2(float x) { return exp2f(x); }
#endif

__device__ __forceinline__ float sigx(float x) {   // sigmoid(x)
    return fast_rcp(1.f + fast_exp2(-x * LOG2E));
}

// ---------------- kernel 0: cast to bf16, exact fp32 row norms, zero accumulators ----------------
__global__ __launch_bounds__(128) void k_prep(
    const float* __restrict__ X, const float* __restrict__ Y,
    __hip_bfloat16* __restrict__ Xb, __hip_bfloat16* __restrict__ Yb,
    float* __restrict__ xn, float* __restrict__ yn,
    float* __restrict__ g5, float* __restrict__ sc, int* __restrict__ syncv)
{
    const int row = blockIdx.x, t = threadIdx.x;
    const float vx = X[row * D + t], vy = Y[row * D + t];
    Xb[row * D + t] = __float2bfloat16(vx);
    Yb[row * D + t] = __float2bfloat16(vy);
    float px = vx * vx, py = vy * vy;
#pragma unroll
    for (int m = 1; m < 64; m <<= 1) { px += __shfl_xor(px, m); py += __shfl_xor(py, m); }
    __shared__ float s[2][2];
    if ((t & 63) == 0) { s[t >> 6][0] = px; s[t >> 6][1] = py; }
    __syncthreads();
    if (t == 0) { xn[row] = s[0][0] + s[1][0]; yn[row] = s[0][1] + s[1][1]; }
    const int g = row * 128 + t;
    if (g < 5 * N) g5[g] = 0.f;
    if (g < 16) sc[g] = 0.f;
    if (g < 4) syncv[g] = 0;
}

// ---------------- main pass: LDS-staging-free MFMA + moment epilogue ----------------
// 512 threads = 8 waves; wave w: wj=(w>>1)*32 (j strip), wi=(w&1)*64 (i strip)
// acc[a][b][r]: j = col0 + wj + a*16 + quad*4 + r,  i = row0 + wi + b*16 + l16
// Per-row outputs (g5[v*N + i]): v0 = sum 1/t (= sum e^L), v1..v4 = sum c^k, c = log2(t/256)
__global__ __launch_bounds__(512, 4) void k_main(
    const __hip_bfloat16* __restrict__ Yb, const __hip_bfloat16* __restrict__ Xb,
    const float* __restrict__ yn, const float* __restrict__ xn,
    float* __restrict__ pos, float* __restrict__ g5)
{
    __shared__ float rowAcc[5][TILE];
    const int tid = threadIdx.x;
    const int bm = blockIdx.y, bn = blockIdx.x;
    const int row0 = bm * TILE, col0 = bn * TILE;   // row0 -> i (Y), col0 -> j (X)
    const int lane = tid & 63, wave = tid >> 6;
    const int wj = (wave >> 1) * 32, wi = (wave & 1) * 64;
    const int l16 = lane & 15, quad = lane >> 4;

    for (int v = tid; v < 5 * TILE; v += 512) (&rowAcc[0][0])[v] = 0.f;
    __syncthreads();

    f32x4 acc[2][4];
#pragma unroll
    for (int a = 0; a < 2; a++)
#pragma unroll
        for (int b = 0; b < 4; b++) acc[a][b] = f32x4{0.f, 0.f, 0.f, 0.f};

    const short8* Xg = (const short8*)(Xb + (size_t)col0 * D);   // j side (A)
    const short8* Yg = (const short8*)(Yb + (size_t)row0 * D);   // i side (B)

#pragma unroll
    for (int kk = 0; kk < 4; ++kk) {
        short8 af[2], bf[4];
#pragma unroll
        for (int t = 0; t < 2; t++)
            af[t] = Xg[(wj + t * 16 + l16) * (D / 8) + kk * 4 + quad];
#pragma unroll
        for (int t = 0; t < 4; t++)
            bf[t] = Yg[(wi + t * 16 + l16) * (D / 8) + kk * 4 + quad];
#pragma unroll
        for (int a = 0; a < 2; a++)
#pragma unroll
            for (int b = 0; b < 4; b++)
                acc[a][b] = __builtin_amdgcn_mfma_f32_16x16x32_bf16(af[a], bf[b], acc[a][b], 0, 0, 0);
    }

    float ynv[4];
#pragma unroll
    for (int b = 0; b < 4; b++) ynv[b] = yn[row0 + wi + b * 16 + l16];

    float sE[4] = {0.f, 0.f, 0.f, 0.f}, s1[4] = {0.f, 0.f, 0.f, 0.f};
    float s2[4] = {0.f, 0.f, 0.f, 0.f}, s3[4] = {0.f, 0.f, 0.f, 0.f}, s4[4] = {0.f, 0.f, 0.f, 0.f};
    const bool diag = (bm == bn);

#pragma unroll
    for (int a = 0; a < 2; a++) {
        const int jl = wj + a * 16 + quad * 4;
        const f32x4 xq = *(const f32x4*)&xn[col0 + jl];
        f32x4 x1;
#pragma unroll
        for (int r = 0; r < 4; r++) x1[r] = xq[r] + 1.f;
#pragma unroll
        for (int b = 0; b < 4; b++) {
            const int il = wi + b * 16 + l16;
#pragma unroll
            for (int r = 0; r < 4; r++) {
                float t = fmaxf(fmaf(-2.f, acc[a][b][r], ynv[b] + x1[r]), 1.f);
                float e = fast_rcp(t);                        // e^L exactly
                float c = fast_log2(t * 0.00390625f);         // log2(t) - 8, centered
                float c2 = c * c;
                sE[b] += e;
                s1[b] += c;
                s2[b] += c2;
                s3[b] = fmaf(c, c2, s3[b]);
                s4[b] = fmaf(c2, c2, s4[b]);
                if (diag && (jl + r) == il)
                    pos[row0 + il] = -LN2 * (c + 8.f);
            }
        }
    }

#pragma unroll
    for (int b = 0; b < 4; b++) {
        const int il = wi + b * 16 + l16;
        float vE = sE[b], v1 = s1[b], v2 = s2[b], v3 = s3[b], v4 = s4[b];
        vE += __shfl_xor(vE, 16); vE += __shfl_xor(vE, 32);
        v1 += __shfl_xor(v1, 16); v1 += __shfl_xor(v1, 32);
        v2 += __shfl_xor(v2, 16); v2 += __shfl_xor(v2, 32);
        v3 += __shfl_xor(v3, 16); v3 += __shfl_xor(v3, 32);
        v4 += __shfl_xor(v4, 16); v4 += __shfl_xor(v4, 32);
        if (lane < 16) {
            atomicAdd(&rowAcc[0][il], vE);
            atomicAdd(&rowAcc[1][il], v1);
            atomicAdd(&rowAcc[2][il], v2);
            atomicAdd(&rowAcc[3][il], v3);
            atomicAdd(&rowAcc[4][il], v4);
        }
    }
    __syncthreads();
    for (int idx = tid; idx < 5 * TILE; idx += 512) {
        int v = idx >> 7, i = idx & 127;
        atomicAdd(&g5[v * N + row0 + i], rowAcc[v][i]);
    }
}

// ---------------- block reduction helper ----------------
__device__ __forceinline__ float block_sum(float v, float* sm)
{
#pragma unroll
    for (int m = 1; m < 64; m <<= 1) v += __shfl_xor(v, m);
    if ((threadIdx.x & 63) == 0) sm[threadIdx.x >> 6] = v;
    __syncthreads();
    float r = 0.f;
    if (threadIdx.x == 0) r = sm[0] + sm[1] + sm[2] + sm[3];
    __syncthreads();
    return r;  // valid on thread 0
}

// ---------------- k_post: LB (exact) + moment-based W/P/Q + outputs. 16 blocks, 1 row/thread ----------------
__global__ __launch_bounds__(256) void k_post(
    const float* __restrict__ pos, const float* __restrict__ g5,
    float* __restrict__ sc, int* __restrict__ syncv, float* __restrict__ out)
{
    __shared__ float sm[4];
    __shared__ float sLB;
    const int tid = threadIdx.x;
    const int i = blockIdx.x * 256 + tid;
    const int nb = gridDim.x;

    const float p  = pos[i];
    const float pe = fast_exp2(p * LOG2E);
    const float E  = g5[i];
    const float C1 = g5[N + i];

    // ---- phase A: exact global reductions -> LB ----
    float bs;
    bs = block_sum(pe, sm);                            if (tid == 0) atomicAdd(&sc[10], bs);
    bs = block_sum(E - pe, sm);                        if (tid == 0) atomicAdd(&sc[11], bs);
    bs = block_sum(-LN2 * (8.f * NFF + C1) - p, sm);   if (tid == 0) atomicAdd(&sc[12], bs);
    bs = block_sum(p, sm);                             if (tid == 0) atomicAdd(&sc[13], bs);
    __threadfence();
    if (tid == 0) {
        int c = __hip_atomic_fetch_add(&syncv[0], 1, __ATOMIC_ACQ_REL, __HIP_MEMORY_SCOPE_AGENT);
        if (c == nb - 1) {
            float S_pos = __hip_atomic_load(&sc[10], __ATOMIC_RELAXED, __HIP_MEMORY_SCOPE_AGENT);
            float S_neg = __hip_atomic_load(&sc[11], __ATOMIC_RELAXED, __HIP_MEMORY_SCOPE_AGENT);
            float TLs   = __hip_atomic_load(&sc[12], __ATOMIC_RELAXED, __HIP_MEMORY_SCOPE_AGENT);
            float Sp    = __hip_atomic_load(&sc[13], __ATOMIC_RELAXED, __HIP_MEMORY_SCOPE_AGENT);
            const float logM = __logf(NFF * (NFF - 1.f));
            float lb2 = __logf(S_neg) - logM;
            float lb1 = __logf(0.5f * ((NFF - 1.f) * S_pos + S_neg)) - logM;
            float LB = lb1 + lb2;
            __hip_atomic_store(&sc[3], LB,  __ATOMIC_RELAXED, __HIP_MEMORY_SCOPE_AGENT);
            __hip_atomic_store(&sc[4], Sp,  __ATOMIC_RELAXED, __HIP_MEMORY_SCOPE_AGENT);
            __hip_atomic_store(&sc[5], TLs, __ATOMIC_RELAXED, __HIP_MEMORY_SCOPE_AGENT);
            __hip_atomic_store(&syncv[1], 1, __ATOMIC_RELEASE, __HIP_MEMORY_SCOPE_AGENT);
        }
        while (__hip_atomic_load(&syncv[1], __ATOMIC_ACQUIRE, __HIP_MEMORY_SCOPE_AGENT) == 0)
            __builtin_amdgcn_s_sleep(8);
        sLB = __hip_atomic_load(&sc[3], __ATOMIC_RELAXED, __HIP_MEMORY_SCOPE_AGENT);
    }
    __syncthreads();
    const float LB = sLB;

    // ---- exact per-row: TP term and diagonal corrections ----
    float Roff = E - pe;
    float pf = p - LB + __logf(0.5f * ((NFF - 1.f) * pe + Roff)) - __logf(NFF - 1.f);
    float tp  = sigx(pf);
    float sgd = sigx(2.f * p - LB);

    // ---- moment-based row sums (4th-order Taylor about row mean of l) ----
    const float C2v = g5[2 * N + i], C3v = g5[3 * N + i], C4v = g5[4 * N + i];
    const float inN = 1.f / NFF;
    float m1 = C1 * inN, e2 = C2v * inN, e3 = C3v * inN, e4 = C4v * inN;
    float k2 = e2 - m1 * m1;
    float k3 = e3 - 3.f * m1 * e2 + 2.f * m1 * m1 * m1;
    float k4 = e4 - 4.f * m1 * e3 + 6.f * m1 * m1 * e2 - 3.f * m1 * m1 * m1 * m1;
    float mu2 = LN2 * LN2 * k2;
    float mu3 = -LN2 * LN2 * LN2 * k3;
    float mu4 = LN2 * LN2 * LN2 * LN2 * k4;
    float mlam = 8.f + m1;                 // mean log2(t)
    float ml = -LN2 * mlam;                // mean l
    float eml = fast_exp2(-mlam);          // e^{ml}
    float den = pe + eml;
    float s = eml * fast_rcp(den);         // sigma(ml - p) = way'
    float w = LN2 * (fast_log2(den) - 1.f);  // way(ml)
    float s1d = s * (1.f - s);
    float a2 = s1d, a3 = s1d * (1.f - 2.f * s), a4 = s1d * (1.f - 6.f * s1d);

    float g = sigx(p + w - LB);
    float g1 = g * (1.f - g), g2 = g1 * (1.f - 2.f * g), g3 = g1 * (1.f - 6.f * g1);
    float g4 = g1 * (1.f - 2.f * g) * (1.f - 12.f * g1);
    float ss = s * s;
    float FP2 = g2 * ss + g1 * a2;
    float FP3 = g3 * ss * s + 3.f * g2 * s * a2 + g1 * a3;
    float FP4 = g4 * ss * ss + 6.f * g3 * ss * a2 + g2 * (3.f * a2 * a2 + 4.f * s * a3) + g1 * a4;

    float h = sigx(w + ml - LB);
    float h1 = h * (1.f - h), h2 = h1 * (1.f - 2.f * h), h3 = h1 * (1.f - 6.f * h1);
    float h4 = h1 * (1.f - 2.f * h) * (1.f - 12.f * h1);
    float b1 = 1.f + s, bb = b1 * b1;
    float FQ2 = h2 * bb + h1 * a2;
    float FQ3 = h3 * bb * b1 + 3.f * h2 * b1 * a2 + h1 * a3;
    float FQ4 = h4 * bb * bb + 6.f * h3 * bb * a2 + h2 * (3.f * a2 * a2 + 4.f * b1 * a3) + h1 * a4;

    float Wi = NFF * (w + 0.5f * a2 * mu2 + (1.f / 6.f) * a3 * mu3 + (1.f / 24.f) * a4 * mu4);
    float Pi = NFF * (g + 0.5f * FP2 * mu2 + (1.f / 6.f) * FP3 * mu3 + (1.f / 24.f) * FP4 * mu4);
    float Qi = NFF * (h + 0.5f * FQ2 * mu2 + (1.f / 6.f) * FQ3 * mu3 + (1.f / 24.f) * FQ4 * mu4);

    bs = block_sum(Wi, sm);  if (tid == 0) atomicAdd(&sc[0], bs);
    bs = block_sum(Pi, sm);  if (tid == 0) atomicAdd(&sc[1], bs);
    bs = block_sum(Qi, sm);  if (tid == 0) atomicAdd(&sc[2], bs);
    bs = block_sum(tp, sm);  if (tid == 0) atomicAdd(&sc[6], bs);
    bs = block_sum(sgd, sm); if (tid == 0) atomicAdd(&sc[7], bs);
    __threadfence();
    if (tid == 0) {
        int c = __hip_atomic_fetch_add(&syncv[2], 1, __ATOMIC_ACQ_REL, __HIP_MEMORY_SCOPE_AGENT);
        if (c == nb - 1) {
            float W   = __hip_atomic_load(&sc[0], __ATOMIC_RELAXED, __HIP_MEMORY_SCOPE_AGENT);
            float P   = __hip_atomic_load(&sc[1], __ATOMIC_RELAXED, __HIP_MEMORY_SCOPE_AGENT);
            float Q   = __hip_atomic_load(&sc[2], __ATOMIC_RELAXED, __HIP_MEMORY_SCOPE_AGENT);
            float tps = __hip_atomic_load(&sc[6], __ATOMIC_RELAXED, __HIP_MEMORY_SCOPE_AGENT);
            float sg  = __hip_atomic_load(&sc[7], __ATOMIC_RELAXED, __HIP_MEMORY_SCOPE_AGENT);
            float Sp  = __hip_atomic_load(&sc[4], __ATOMIC_RELAXED, __HIP_MEMORY_SCOPE_AGENT);
            float TLs = __hip_atomic_load(&sc[5], __ATOMIC_RELAXED, __HIP_MEMORY_SCOPE_AGENT);
            const float M = NFF * (NFF - 1.f);
            float Wo  = W - Sp;          // off-diagonal sum of way
            float SGP = P - sg;
            float SGN = Q - sg;
            float TP = tps * (1.f / NFF);
            float o0 = Sp / NFF + Wo / M - LB;
            float o1 = Wo / M + TLs / M - LB;
            float o2 = SGP / M, o3 = SGN / M;
            out[0] = o0;
            out[1] = o1;
            out[2] = o2;
            out[3] = o3;
            out[4] = (TP + 1.f - o3) * 0.5f;
            out[5] = TP;
            out[6] = TP / (TP + o3);
            out[7] = LB;
            out[8] = -o0 + 2.0f;
        }
    }
}

extern "C" void kernel_launch(void* const* d_in, const int* in_sizes, int n_in,
                              void* d_out, int out_size, void* d_ws, size_t ws_size,
                              hipStream_t stream)
{
    const float* X = (const float*)d_in[0];  // z_x (j / columns of logits)
    const float* Y = (const float*)d_in[1];  // z_y (i / rows of logits)
    float* out = (float*)d_out;

    char* ws = (char*)d_ws;
    __hip_bfloat16* Yb = (__hip_bfloat16*)(ws);
    __hip_bfloat16* Xb = (__hip_bfloat16*)(ws + (1 << 20));
    float* yn  = (float*)(ws + (2 << 20));
    float* xn  = yn + N;
    float* pos = xn + N;
    float* g5  = pos + N;          // 5*N per-row accumulators (E, C1..C4)
    float* sc  = g5 + 5 * N;       // 16 scalars
    int*   syncv = (int*)(sc + 16);

    k_prep<<<N, 128, 0, stream>>>(X, Y, Xb, Yb, xn, yn, g5, sc, syncv);
    k_main<<<dim3(N / TILE, N / TILE), 512, 0, stream>>>(Yb, Xb, yn, xn, pos, g5);
    k_post<<<16, 256, 0, stream>>>(pos, g5, sc, syncv, out);
}

// Round 9
// 97.068 us; speedup vs baseline: 1.1711x; 1.0811x over previous
//
#include <hip/hip_runtime.h>
#include <hip/hip_bf16.h>

#define N 4096
#define D 128
#define TILE 128
#define NFF 4096.0f

typedef __attribute__((ext_vector_type(8))) short short8;
typedef __attribute__((ext_vector_type(4))) float f32x4;

#define LOG2E 1.44269504088896340736f
#define LN2   0.69314718055994530942f

#if __has_builtin(__builtin_amdgcn_rcpf)
__device__ __forceinline__ float fast_rcp(float x) { return __builtin_amdgcn_rcpf(x); }
#else
__device__ __forceinline__ float fast_rcp(float x) { return 1.f / x; }
#endif
#if __has_builtin(__builtin_amdgcn_logf)
__device__ __forceinline__ float fast_log2(float x) { return __builtin_amdgcn_logf(x); }
#else
__device__ __forceinline__ float fast_log2(float x) { return __log2f(x); }
#endif
#if __has_builtin(__builtin_amdgcn_exp2f)
__device__ __forceinline__ float fast_exp2(float x) { return __builtin_amdgcn_exp2f(x); }
#else
__device__ __forceinline__ float fast_exp2(float x) { return exp2f(x); }
#endif

__device__ __forceinline__ float sigx(float x) {   // sigmoid(x)
    return fast_rcp(1.f + fast_exp2(-x * LOG2E));
}

__device__ __forceinline__ unsigned short bf16_of(float v) {
    __hip_bfloat16 h = __float2bfloat16(v);
    return *reinterpret_cast<unsigned short*>(&h);
}

// ---------------- kernel 0: cast to bf16 (float4), exact fp32 row norms, zero accumulators ----------------
// 512 blocks x 256 threads; 8 rows/block, 32 threads/row, 4 elems/thread
__global__ __launch_bounds__(256) void k_prep(
    const float* __restrict__ X, const float* __restrict__ Y,
    __hip_bfloat16* __restrict__ Xb, __hip_bfloat16* __restrict__ Yb,
    float* __restrict__ xn, float* __restrict__ yn,
    float* __restrict__ g4, float* __restrict__ sc, int* __restrict__ syncv)
{
    const int tid = threadIdx.x, bid = blockIdx.x;
    const int row = bid * 8 + (tid >> 5);
    const int c4 = (tid & 31) * 4;
    const float4 vx = *(const float4*)&X[row * D + c4];
    const float4 vy = *(const float4*)&Y[row * D + c4];
    ushort4 hx, hy;
    hx.x = bf16_of(vx.x); hx.y = bf16_of(vx.y); hx.z = bf16_of(vx.z); hx.w = bf16_of(vx.w);
    hy.x = bf16_of(vy.x); hy.y = bf16_of(vy.y); hy.z = bf16_of(vy.z); hy.w = bf16_of(vy.w);
    *(ushort4*)&Xb[row * D + c4] = hx;
    *(ushort4*)&Yb[row * D + c4] = hy;
    float px = vx.x * vx.x + vx.y * vx.y + vx.z * vx.z + vx.w * vx.w;
    float py = vy.x * vy.x + vy.y * vy.y + vy.z * vy.z + vy.w * vy.w;
#pragma unroll
    for (int m = 1; m < 32; m <<= 1) { px += __shfl_xor(px, m); py += __shfl_xor(py, m); }
    if ((tid & 31) == 0) { xn[row] = px; yn[row] = py; }
    const int gid = bid * 256 + tid;
    if (gid < 4 * N) g4[gid] = 0.f;
    if (gid < 16) sc[gid] = 0.f;
    if (gid < 4) syncv[gid] = 0;
}

// ---------------- main pass: LDS-staging-free MFMA + raw-e-moment epilogue ----------------
// acc[a][b][r]: j = col0 + wj + a*16 + quad*4 + r,  i = row0 + wi + b*16 + l16
// Per-row outputs (g4[v*N + i]): v = Σ e^(v+1),  e = 1/t = exp(L) exactly
__global__ __launch_bounds__(256) void k_main(
    const __hip_bfloat16* __restrict__ Yb, const __hip_bfloat16* __restrict__ Xb,
    const float* __restrict__ yn, const float* __restrict__ xn,
    float* __restrict__ pos, float* __restrict__ g4)
{
    __shared__ float rowAcc[4][TILE];
    const int tid = threadIdx.x;
    const int bm = blockIdx.y, bn = blockIdx.x;
    const int row0 = bm * TILE, col0 = bn * TILE;   // row0 -> i (Y), col0 -> j (X)
    const int lane = tid & 63, wave = tid >> 6;
    const int wj = (wave >> 1) * 64, wi = (wave & 1) * 64;
    const int l16 = lane & 15, quad = lane >> 4;

    for (int v = tid; v < 4 * TILE; v += 256) (&rowAcc[0][0])[v] = 0.f;
    __syncthreads();

    f32x4 acc[4][4];
#pragma unroll
    for (int a = 0; a < 4; a++)
#pragma unroll
        for (int b = 0; b < 4; b++) acc[a][b] = f32x4{0.f, 0.f, 0.f, 0.f};

    const short8* Xg = (const short8*)(Xb + (size_t)col0 * D);   // j side (A)
    const short8* Yg = (const short8*)(Yb + (size_t)row0 * D);   // i side (B)

#pragma unroll
    for (int kk = 0; kk < 4; ++kk) {
        short8 af[4], bf[4];
#pragma unroll
        for (int t = 0; t < 4; t++) {
            af[t] = Xg[(wj + t * 16 + l16) * (D / 8) + kk * 4 + quad];
            bf[t] = Yg[(wi + t * 16 + l16) * (D / 8) + kk * 4 + quad];
        }
#pragma unroll
        for (int a = 0; a < 4; a++)
#pragma unroll
            for (int b = 0; b < 4; b++)
                acc[a][b] = __builtin_amdgcn_mfma_f32_16x16x32_bf16(af[a], bf[b], acc[a][b], 0, 0, 0);
    }

    float ynv[4];
#pragma unroll
    for (int b = 0; b < 4; b++) ynv[b] = yn[row0 + wi + b * 16 + l16];

    float o1[4] = {0.f, 0.f, 0.f, 0.f}, o2[4] = {0.f, 0.f, 0.f, 0.f};
    float o3[4] = {0.f, 0.f, 0.f, 0.f}, o4[4] = {0.f, 0.f, 0.f, 0.f};

#pragma unroll
    for (int a = 0; a < 4; a++) {
        const f32x4 xq = *(const f32x4*)&xn[col0 + wj + a * 16 + quad * 4];
        f32x4 x1;
#pragma unroll
        for (int r = 0; r < 4; r++) x1[r] = xq[r] + 1.f;
#pragma unroll
        for (int b = 0; b < 4; b++) {
#pragma unroll
            for (int r = 0; r < 4; r++) {
                float t = fmaxf(fmaf(-2.f, acc[a][b][r], ynv[b] + x1[r]), 1.f);
                float e = fast_rcp(t);       // e^L exactly
                float e2 = e * e;
                o1[b] += e;
                o2[b] += e2;
                o3[b] = fmaf(e, e2, o3[b]);
                o4[b] = fmaf(e2, e2, o4[b]);
            }
        }
    }

    // diagonal pos store (exact log), outside the hot loop; only 8 blocks take this path
    if (bm == bn && wi == wj && quad == (l16 >> 2)) {
        const int rr = l16 & 3;
#pragma unroll
        for (int b = 0; b < 4; b++) {
            float dacc;
#pragma unroll
            for (int r = 0; r < 4; r++) if (rr == r) dacc = acc[b][b][r];
            float t = fmaxf(fmaf(-2.f, dacc, ynv[b] + xn[col0 + wj + b * 16 + l16] + 1.f), 1.f);
            pos[row0 + wi + b * 16 + l16] = -LN2 * fast_log2(t);
        }
    }

#pragma unroll
    for (int b = 0; b < 4; b++) {
        const int il = wi + b * 16 + l16;
        float v1 = o1[b], v2 = o2[b], v3 = o3[b], v4 = o4[b];
        v1 += __shfl_xor(v1, 16); v1 += __shfl_xor(v1, 32);
        v2 += __shfl_xor(v2, 16); v2 += __shfl_xor(v2, 32);
        v3 += __shfl_xor(v3, 16); v3 += __shfl_xor(v3, 32);
        v4 += __shfl_xor(v4, 16); v4 += __shfl_xor(v4, 32);
        if (lane < 16) {
            atomicAdd(&rowAcc[0][il], v1);
            atomicAdd(&rowAcc[1][il], v2);
            atomicAdd(&rowAcc[2][il], v3);
            atomicAdd(&rowAcc[3][il], v4);
        }
    }
    __syncthreads();
    for (int idx = tid; idx < 4 * TILE; idx += 256) {
        int v = idx >> 7, i = idx & 127;
        atomicAdd(&g4[v * N + row0 + i], rowAcc[v][i]);
    }
}

// ---------------- block reduction helper ----------------
__device__ __forceinline__ float block_sum(float v, float* sm)
{
#pragma unroll
    for (int m = 1; m < 64; m <<= 1) v += __shfl_xor(v, m);
    if ((threadIdx.x & 63) == 0) sm[threadIdx.x >> 6] = v;
    __syncthreads();
    float r = 0.f;
    if (threadIdx.x == 0) r = sm[0] + sm[1] + sm[2] + sm[3];
    __syncthreads();
    return r;  // valid on thread 0
}

// ---------------- k_post: LB (exact) + e-space-moment W/P/Q + outputs. 16 blocks, 1 row/thread ----------------
__global__ __launch_bounds__(256) void k_post(
    const float* __restrict__ pos, const float* __restrict__ g4,
    float* __restrict__ sc, int* __restrict__ syncv, float* __restrict__ out)
{
    __shared__ float sm[4];
    __shared__ float sLB;
    const int tid = threadIdx.x;
    const int i = blockIdx.x * 256 + tid;
    const int nb = gridDim.x;

    const float p  = pos[i];
    const float pe = fast_exp2(p * LOG2E);
    const float E1 = g4[i], E2 = g4[N + i], E3 = g4[2 * N + i], E4 = g4[3 * N + i];

    // central moments of e over the row (diag included; exact-diag corrections applied later)
    const float inN = 1.f / NFF;
    const float m1 = E1 * inN;
    const float M2 = E2 * inN, M3 = E3 * inN, M4 = E4 * inN;
    const float v2 = M2 - m1 * m1;
    const float v3 = M3 - 3.f * m1 * M2 + 2.f * m1 * m1 * m1;
    const float v4 = M4 - 4.f * m1 * M3 + 6.f * m1 * m1 * M2 - 3.f * m1 * m1 * m1 * m1;

    // Sum_j ln e_j via log-series around m1
    const float im = fast_rcp(m1), im2 = im * im;
    const float rowL = NFF * (LN2 * fast_log2(m1) - 0.5f * v2 * im2
                              + (1.f / 3.f) * v3 * im2 * im - 0.25f * v4 * im2 * im2);

    // ---- phase A: exact global reductions -> LB ----
    float bs;
    bs = block_sum(pe, sm);         if (tid == 0) atomicAdd(&sc[10], bs);
    bs = block_sum(E1 - pe, sm);    if (tid == 0) atomicAdd(&sc[11], bs);
    bs = block_sum(rowL - p, sm);   if (tid == 0) atomicAdd(&sc[12], bs);
    bs = block_sum(p, sm);          if (tid == 0) atomicAdd(&sc[13], bs);
    __threadfence();
    if (tid == 0) {
        int c = __hip_atomic_fetch_add(&syncv[0], 1, __ATOMIC_ACQ_REL, __HIP_MEMORY_SCOPE_AGENT);
        if (c == nb - 1) {
            float S_pos = __hip_atomic_load(&sc[10], __ATOMIC_RELAXED, __HIP_MEMORY_SCOPE_AGENT);
            float S_neg = __hip_atomic_load(&sc[11], __ATOMIC_RELAXED, __HIP_MEMORY_SCOPE_AGENT);
            float TLs   = __hip_atomic_load(&sc[12], __ATOMIC_RELAXED, __HIP_MEMORY_SCOPE_AGENT);
            float Sp    = __hip_atomic_load(&sc[13], __ATOMIC_RELAXED, __HIP_MEMORY_SCOPE_AGENT);
            const float logM = __logf(NFF * (NFF - 1.f));
            float lb2 = __logf(S_neg) - logM;
            float lb1 = __logf(0.5f * ((NFF - 1.f) * S_pos + S_neg)) - logM;
            float LB = lb1 + lb2;
            __hip_atomic_store(&sc[3], LB,  __ATOMIC_RELAXED, __HIP_MEMORY_SCOPE_AGENT);
            __hip_atomic_store(&sc[4], Sp,  __ATOMIC_RELAXED, __HIP_MEMORY_SCOPE_AGENT);
            __hip_atomic_store(&sc[5], TLs, __ATOMIC_RELAXED, __HIP_MEMORY_SCOPE_AGENT);
            __hip_atomic_store(&syncv[1], 1, __ATOMIC_RELEASE, __HIP_MEMORY_SCOPE_AGENT);
        }
        while (__hip_atomic_load(&syncv[1], __ATOMIC_ACQUIRE, __HIP_MEMORY_SCOPE_AGENT) == 0)
            __builtin_amdgcn_s_sleep(8);
        sLB = __hip_atomic_load(&sc[3], __ATOMIC_RELAXED, __HIP_MEMORY_SCOPE_AGENT);
    }
    __syncthreads();
    const float LB = sLB;
    const float C2 = 2.f * fast_exp2(LB * LOG2E);

    // ---- exact per-row: TP term and diag sigmoid correction ----
    float Roff = E1 - pe;
    float pf = p - LB + __logf(0.5f * ((NFF - 1.f) * pe + Roff)) - __logf(NFF - 1.f);
    float tp  = sigx(pf);
    float sgd = sigx(2.f * p - LB);

    // ---- e-space Taylor row sums ----
    // way: w(e) = ln(pe + e) - ln2
    const float U = pe + m1;
    const float r1 = fast_rcp(U), r12 = r1 * r1;
    float Wi = NFF * (LN2 * (fast_log2(U) - 1.f) - 0.5f * v2 * r12
                      + (1.f / 3.f) * v3 * r12 * r1 - 0.25f * v4 * r12 * r12);

    // P: F(e) = z/(z+C2), z = pe*(pe+e)  [= sigmoid(pos+way-LB)]
    const float z0 = pe * U;
    const float rp = fast_rcp(z0 + C2);
    const float cp = C2 * rp * rp;      // F' / pe
    const float pe2 = pe * pe;
    float Pi = NFF * (z0 * rp - cp * rp * pe2 * v2
                      + cp * rp * rp * pe2 * pe * v3
                      - cp * rp * rp * rp * pe2 * pe2 * v4);

    // Q: G(e) = y/(y+C2), y = e*(pe+e)  [= sigmoid(way+L-LB)]
    const float y0 = m1 * U;
    const float rq = fast_rcp(y0 + C2);
    const float cq  = C2 * rq * rq;             // dG/dy
    const float Gy2 = -2.f * cq * rq;           // d2G/dy2
    const float Gy3 = 6.f * cq * rq * rq;       // d3G/dy3
    const float Gy4 = -24.f * cq * rq * rq * rq;
    const float yp = pe + 2.f * m1;             // dy/de (d2y/de2 = 2)
    const float yp2 = yp * yp;
    float G2 = Gy2 * yp2 + 2.f * cq;
    float G3 = Gy3 * yp2 * yp + 6.f * Gy2 * yp;
    float G4 = Gy4 * yp2 * yp2 + 12.f * Gy3 * yp2 + 12.f * Gy2;
    float Qi = NFF * (y0 * rq + 0.5f * G2 * v2 + (1.f / 6.f) * G3 * v3 + (1.f / 24.f) * G4 * v4);

    bs = block_sum(Wi, sm);  if (tid == 0) atomicAdd(&sc[0], bs);
    bs = block_sum(Pi, sm);  if (tid == 0) atomicAdd(&sc[1], bs);
    bs = block_sum(Qi, sm);  if (tid == 0) atomicAdd(&sc[2], bs);
    bs = block_sum(tp, sm);  if (tid == 0) atomicAdd(&sc[6], bs);
    bs = block_sum(sgd, sm); if (tid == 0) atomicAdd(&sc[7], bs);
    __threadfence();
    if (tid == 0) {
        int c = __hip_atomic_fetch_add(&syncv[2], 1, __ATOMIC_ACQ_REL, __HIP_MEMORY_SCOPE_AGENT);
        if (c == nb - 1) {
            float W   = __hip_atomic_load(&sc[0], __ATOMIC_RELAXED, __HIP_MEMORY_SCOPE_AGENT);
            float P   = __hip_atomic_load(&sc[1], __ATOMIC_RELAXED, __HIP_MEMORY_SCOPE_AGENT);
            float Q   = __hip_atomic_load(&sc[2], __ATOMIC_RELAXED, __HIP_MEMORY_SCOPE_AGENT);
            float tps = __hip_atomic_load(&sc[6], __ATOMIC_RELAXED, __HIP_MEMORY_SCOPE_AGENT);
            float sg  = __hip_atomic_load(&sc[7], __ATOMIC_RELAXED, __HIP_MEMORY_SCOPE_AGENT);
            float Sp  = __hip_atomic_load(&sc[4], __ATOMIC_RELAXED, __HIP_MEMORY_SCOPE_AGENT);
            float TLs = __hip_atomic_load(&sc[5], __ATOMIC_RELAXED, __HIP_MEMORY_SCOPE_AGENT);
            const float M = NFF * (NFF - 1.f);
            float Wo  = W - Sp;          // off-diagonal sum of way
            float SGP = P - sg;
            float SGN = Q - sg;
            float TP = tps * (1.f / NFF);
            float o0 = Sp / NFF + Wo / M - LB;
            float o1 = Wo / M + TLs / M - LB;
            float o2 = SGP / M, o3 = SGN / M;
            out[0] = o0;
            out[1] = o1;
            out[2] = o2;
            out[3] = o3;
            out[4] = (TP + 1.f - o3) * 0.5f;
            out[5] = TP;
            out[6] = TP / (TP + o3);
            out[7] = LB;
            out[8] = -o0 + 2.0f;
        }
    }
}

extern "C" void kernel_launch(void* const* d_in, const int* in_sizes, int n_in,
                              void* d_out, int out_size, void* d_ws, size_t ws_size,
                              hipStream_t stream)
{
    const float* X = (const float*)d_in[0];  // z_x (j / columns of logits)
    const float* Y = (const float*)d_in[1];  // z_y (i / rows of logits)
    float* out = (float*)d_out;

    char* ws = (char*)d_ws;
    __hip_bfloat16* Yb = (__hip_bfloat16*)(ws);
    __hip_bfloat16* Xb = (__hip_bfloat16*)(ws + (1 << 20));
    float* yn  = (float*)(ws + (2 << 20));
    float* xn  = yn + N;
    float* pos = xn + N;
    float* g4  = pos + N;          // 4*N per-row raw e-moments
    float* sc  = g4 + 4 * N;       // 16 scalars
    int*   syncv = (int*)(sc + 16);

    k_prep<<<512, 256, 0, stream>>>(X, Y, Xb, Yb, xn, yn, g4, sc, syncv);
    k_main<<<dim3(N / TILE, N / TILE), 256, 0, stream>>>(Yb, Xb, yn, xn, pos, g4);
    k_post<<<16, 256, 0, stream>>>(pos, g4, sc, syncv, out);
}